// Round 3
// baseline (34.325 us; speedup 1.0000x reference)
//
#include <hip/hip_runtime.h>

#define D_  128
#define K2_ 256
#define BM  16

typedef short bf16x8 __attribute__((ext_vector_type(8)));
typedef float f32x4  __attribute__((ext_vector_type(4)));

__device__ __forceinline__ unsigned short f2bf(float f) {
  unsigned int u = __float_as_uint(f);
  u += 0x7fffu + ((u >> 16) & 1u);       // round-to-nearest-even
  return (unsigned short)(u >> 16);
}
__device__ __forceinline__ float bf2f(unsigned short s) {
  return __uint_as_float(((unsigned int)s) << 16);
}

// ---------------- prep: pack weights into MFMA-fragment-ordered bf16 ----------------
// Pack p, fragment (c16,k32): elem addr = p*32768 + (c16*K32 + k32)*512 + lane*8 + e
//   lane = (c%16) + 16*((k%32)/8), e = k%8
// p0: B[k][c]=W1[c*128+k] hi   (P1, K=128, c<256)
// p1: same, lo residual        (P1)
// p2: B[k][c]=W2[c*256+k] hi   (P2, K=256, c<128)
// p3: B[k][c]=W2[k*256+c] hi   (P3, K=128, c<256)
// p4: B[k][c]=W1[k*128+c] hi   (P4, K=256, c<128)
__global__ __launch_bounds__(256) void prep_pack(
    const float* __restrict__ W1, const float* __restrict__ W2,
    unsigned short* __restrict__ ws)
{
  int idx = blockIdx.x * 256 + threadIdx.x;      // 640 blocks -> 163840 elems
  int p   = idx >> 15;
  int r   = idx & 32767;
  int e   = r & 7;
  int l   = (r >> 3) & 63;
  int blk = r >> 9;
  int sh  = (p == 2 || p == 4) ? 3 : 2;          // log2(K32)
  int k32 = blk & ((1 << sh) - 1);
  int c16 = blk >> sh;
  int c = c16 * 16 + (l & 15);
  int k = k32 * 32 + (l >> 4) * 8 + e;
  float v;
  if (p <= 1)      v = W1[c * 128 + k];
  else if (p == 2) v = W2[c * 256 + k];
  else if (p == 3) v = W2[k * 256 + c];
  else             v = W1[k * 128 + c];
  unsigned short h = f2bf(v);
  ws[idx] = (p == 1) ? f2bf(v - bf2f(h)) : h;
}

// ---------------- main fused kernel ----------------
__global__ __launch_bounds__(256) void fused_jvp_kernel(
    const float* __restrict__ input_,
    const float* __restrict__ W1, const float* __restrict__ b1,
    const float* __restrict__ b2,
    const unsigned short* __restrict__ wp,
    float* __restrict__ out)
{
  // aliased LDS pool (28 KiB): ub aliases xb, rb aliases m2b
  __shared__ __align__(16) unsigned short sh[14336];
  unsigned short* xb  = sh;          // 16x128 (x hi)      [dead after P1 K-loop]
  unsigned short* xlb = sh + 2048;   // 16x128 (x lo)
  unsigned short* vb  = sh + 4096;   // 16x128 (v bf16)
  unsigned short* hb  = sh + 6144;   // 16x256 (h)
  unsigned short* m2b = sh + 10240;  // 16x256 (mask*w)    [dead after P2 K-loop]
  unsigned short* ub  = sh;          // 16x128 (v^2*coef)  alias xb
  unsigned short* rb  = sh + 10240;  // 16x256 (mask*p)    alias m2b

  const unsigned short* p0 = wp;
  const unsigned short* p1 = wp + 32768;
  const unsigned short* p2 = wp + 65536;
  const unsigned short* p3 = wp + 98304;
  const unsigned short* p4 = wp + 131072;

  const int tid  = threadIdx.x;
  const int lane = tid & 63;
  const int wv   = tid >> 6;        // wave 0..3
  const int l15  = lane & 15;
  const int lg   = lane >> 4;       // 0..3
  const long rowbase = (long)blockIdx.x * BM;

  // ---- P0: stage x (hi+lo) and v as bf16 (swizzled); out[:, :128] = v (exact f32)
  #pragma unroll
  for (int it = 0; it < 4; ++it) {
    int flat4 = it * 256 + tid;          // float4 index in 16x256 tile
    int row   = flat4 >> 6;              // 64 float4 per row
    int col   = (flat4 & 63) * 4;
    const float4 val = *(const float4*)(input_ + (rowbase + row) * 256 + col);
    ushort4 hq;
    hq.x = f2bf(val.x); hq.y = f2bf(val.y); hq.z = f2bf(val.z); hq.w = f2bf(val.w);
    if (col < D_) {
      ushort4 lq;
      lq.x = f2bf(val.x - bf2f(hq.x));
      lq.y = f2bf(val.y - bf2f(hq.y));
      lq.z = f2bf(val.z - bf2f(hq.z));
      lq.w = f2bf(val.w - bf2f(hq.w));
      int idx = (row * D_ + col) ^ ((row & 7) << 3);
      *(ushort4*)(&xb[idx])  = hq;
      *(ushort4*)(&xlb[idx]) = lq;
    } else {
      int c = col - D_;
      int idx = (row * D_ + c) ^ ((row & 7) << 3);
      *(ushort4*)(&vb[idx]) = hq;
      *(float4*)(out + (rowbase + row) * 256 + c) = val;   // out[:, :128] = v
    }
  }
  __syncthreads();

  // A-fragment from swizzled LDS tile (row-major, stride S elements)
  auto load_afrag = [&](const unsigned short* tile, int S, int kbase) -> bf16x8 {
    int row = l15;
    int idx = (row * S + kbase + lg * 8) ^ ((row & 7) << 3);
    return *(const bf16x8*)(&tile[idx]);
  };
  // packed B-fragment: one coalesced 16B/lane load
  auto ldB = [&](const unsigned short* pk, int K32, int c16, int k32) -> bf16x8 {
    return *(const bf16x8*)(pk + (((c16 * K32 + k32) << 9) + (lane << 3)));
  };

  // ---- P1: z1 = x*W1^T + b1 (split precision) ; w = v*W1^T   (out 16x256)
  f32x4 accz[4] = {};
  f32x4 accw[4] = {};
  #pragma unroll
  for (int k32 = 0; k32 < 4; ++k32) {
    bf16x8 axh = load_afrag(xb,  D_, k32 * 32);
    bf16x8 axl = load_afrag(xlb, D_, k32 * 32);
    bf16x8 av  = load_afrag(vb,  D_, k32 * 32);
    #pragma unroll
    for (int nt = 0; nt < 4; ++nt) {
      int c16 = wv * 4 + nt;
      bf16x8 bh = ldB(p0, 4, c16, k32);
      bf16x8 bl = ldB(p1, 4, c16, k32);
      accz[nt] = __builtin_amdgcn_mfma_f32_16x16x32_bf16(axh, bh, accz[nt], 0, 0, 0);
      accz[nt] = __builtin_amdgcn_mfma_f32_16x16x32_bf16(axh, bl, accz[nt], 0, 0, 0);
      accz[nt] = __builtin_amdgcn_mfma_f32_16x16x32_bf16(axl, bh, accz[nt], 0, 0, 0);
      accw[nt] = __builtin_amdgcn_mfma_f32_16x16x32_bf16(av,  bh, accw[nt], 0, 0, 0);
    }
  }
  #pragma unroll
  for (int nt = 0; nt < 4; ++nt) {
    int cg = wv * 64 + nt * 16 + l15;
    float bias = b1[cg];
    #pragma unroll
    for (int q = 0; q < 4; ++q) {
      int rg = lg * 4 + q;
      float z = accz[nt][q] + bias;
      if (__builtin_expect(fabsf(z) < 1e-4f, 0)) {
        // borderline ReLU: recompute exactly in f64 (rare)
        const float* xr  = input_ + (rowbase + rg) * 256;
        const float* w1r = W1 + (size_t)cg * D_;
        double zd = (double)bias;
        for (int k = 0; k < D_; ++k) zd += (double)xr[k] * (double)w1r[k];
        z = (float)zd;
      }
      float hv = z > 0.f ? z : 0.f;
      float mw = z > 0.f ? accw[nt][q] : 0.f;
      int idx = (rg * K2_ + cg) ^ ((rg & 7) << 3);
      hb[idx]  = f2bf(hv);
      m2b[idx] = f2bf(mw);
    }
  }
  __syncthreads();

  // ---- P2: sdot = h*W2^T ; y = m2*W2^T  (out 16x128, wave owns 32 cols)
  f32x4 accs[2] = {};
  f32x4 accy[2] = {};
  #pragma unroll
  for (int k32 = 0; k32 < 8; ++k32) {
    bf16x8 ah = load_afrag(hb,  K2_, k32 * 32);
    bf16x8 am = load_afrag(m2b, K2_, k32 * 32);
    #pragma unroll
    for (int nt = 0; nt < 2; ++nt) {
      int c16 = wv * 2 + nt;
      bf16x8 bw = ldB(p2, 8, c16, k32);
      accs[nt] = __builtin_amdgcn_mfma_f32_16x16x32_bf16(ah, bw, accs[nt], 0, 0, 0);
      accy[nt] = __builtin_amdgcn_mfma_f32_16x16x32_bf16(am, bw, accy[nt], 0, 0, 0);
    }
  }
  float coefr[2][4], ginvr[2][4];
  #pragma unroll
  for (int nt = 0; nt < 2; ++nt) {
    int cg = wv * 32 + nt * 16 + l15;
    float bias = b2[cg];
    float sgn  = (cg < 4) ? -1.f : 1.f;
    #pragma unroll
    for (int q = 0; q < 4; ++q) {
      int rg = lg * 4 + q;
      float sv = 1.f / (1.f + __expf(-(accs[nt][q] + bias)));
      float cf = sgn * sv * (1.f - sv);
      float gi = 1.f / ((sv + 0.618f) * sgn);
      coefr[nt][q] = cf;
      ginvr[nt][q] = gi;
      float vvf = input_[(rowbase + rg) * 256 + 128 + cg];   // exact f32 v
      int idxd = (rg * D_ + cg) ^ ((rg & 7) << 3);
      ub[idxd] = f2bf(vvf * vvf * cf);          // u = v^2 * coef  (aliases xb)
    }
  }
  __syncthreads();

  // ---- P3: p = u*W2  (out 16x256) ; r = mask .* p
  f32x4 accp[4] = {};
  #pragma unroll
  for (int k32 = 0; k32 < 4; ++k32) {
    bf16x8 au = load_afrag(ub, D_, k32 * 32);
    #pragma unroll
    for (int nt = 0; nt < 4; ++nt) {
      int c16 = wv * 4 + nt;
      bf16x8 bw = ldB(p3, 4, c16, k32);
      accp[nt] = __builtin_amdgcn_mfma_f32_16x16x32_bf16(au, bw, accp[nt], 0, 0, 0);
    }
  }
  #pragma unroll
  for (int nt = 0; nt < 4; ++nt) {
    int cg = wv * 64 + nt * 16 + l15;
    #pragma unroll
    for (int q = 0; q < 4; ++q) {
      int rg = lg * 4 + q;
      int idx = (rg * K2_ + cg) ^ ((rg & 7) << 3);
      rb[idx] = (hb[idx] != 0) ? f2bf(accp[nt][q]) : (unsigned short)0;
    }
  }
  __syncthreads();

  // ---- P4: t1pre = r*W1  (out 16x128) ; final epilogue
  f32x4 acct[2] = {};
  #pragma unroll
  for (int k32 = 0; k32 < 8; ++k32) {
    bf16x8 ar = load_afrag(rb, K2_, k32 * 32);
    #pragma unroll
    for (int nt = 0; nt < 2; ++nt) {
      int c16 = wv * 2 + nt;
      bf16x8 bw = ldB(p4, 8, c16, k32);
      acct[nt] = __builtin_amdgcn_mfma_f32_16x16x32_bf16(ar, bw, acct[nt], 0, 0, 0);
    }
  }
  #pragma unroll
  for (int nt = 0; nt < 2; ++nt) {
    int cg = wv * 32 + nt * 16 + l15;
    #pragma unroll
    for (int q = 0; q < 4; ++q) {
      int rg = lg * 4 + q;
      float vvf = input_[(rowbase + rg) * 256 + 128 + cg];   // exact f32 v
      float gi  = ginvr[nt][q];
      float dv  = -gi * acct[nt][q]
                + 2.f * vvf * gi * coefr[nt][q] * accy[nt][q];
      out[(rowbase + rg) * 256 + 128 + cg] = dv;
    }
  }
}

extern "C" void kernel_launch(void* const* d_in, const int* in_sizes, int n_in,
                              void* d_out, int out_size, void* d_ws, size_t ws_size,
                              hipStream_t stream) {
  const float* input_ = (const float*)d_in[1];
  const float* W1     = (const float*)d_in[2];
  const float* b1     = (const float*)d_in[3];
  const float* W2     = (const float*)d_in[4];
  const float* b2     = (const float*)d_in[5];
  float* out = (float*)d_out;
  unsigned short* wpack = (unsigned short*)d_ws;
  int N = in_sizes[1] / (2 * D_);

  prep_pack<<<dim3(640), dim3(256), 0, stream>>>(W1, W2, wpack);
  fused_jvp_kernel<<<dim3(N / BM), dim3(256), 0, stream>>>(input_, W1, b1, b2, wpack, out);
}